// Round 1
// baseline (417.854 us; speedup 1.0000x reference)
//
#include <hip/hip_runtime.h>
#include <hip/hip_bf16.h>
#include <math.h>

typedef short bf8v __attribute__((ext_vector_type(8)));   // 8 bf16 (4 VGPRs)
typedef float f32x4 __attribute__((ext_vector_type(4)));
typedef unsigned short u16;
typedef unsigned int u32;

#define DEV __device__ __forceinline__

static constexpr int S_ = 2048;
static constexpr int H_ = 16;
static constexpr int D_ = 64;
static constexpr int DM = 1024;

DEV u16 f2bf(float f) {
  union { float f; u32 u; } v; v.f = f;
  return (u16)((v.u + 0x7fffu + ((v.u >> 16) & 1u)) >> 16);  // RNE
}

DEV void gld16(u16* lds, const u16* g) {
  __builtin_amdgcn_global_load_lds(
      (const __attribute__((address_space(1))) u32*)g,
      (__attribute__((address_space(3))) u32*)lds, 16, 0, 0);
}

DEV f32x4 MFMA(bf8v a, bf8v b, f32x4 c) {
  return __builtin_amdgcn_mfma_f32_16x16x32_bf16(a, b, c, 0, 0, 0);
}

// ---------------- converts ----------------
__global__ void k_cvt_x(const float* __restrict__ x, u16* __restrict__ xb, int n4) {
  int i = blockIdx.x * blockDim.x + threadIdx.x;
  int stride = gridDim.x * blockDim.x;
  for (; i < n4; i += stride) {
    float4 v = ((const float4*)x)[i];
    ushort4 o;
    o.x = f2bf(v.x); o.y = f2bf(v.y); o.z = f2bf(v.z); o.w = f2bf(v.w);
    ((ushort4*)xb)[i] = o;
  }
}

// W [K][N] f32 -> WT [N][K] bf16, 64x64 LDS tile transpose; z selects matrix
__global__ void k_cvt_wT4(const float* __restrict__ W0, const float* __restrict__ W1,
                          const float* __restrict__ W2, const float* __restrict__ W3,
                          u16* __restrict__ T0, u16* __restrict__ T1,
                          u16* __restrict__ T2, u16* __restrict__ T3) {
  __shared__ float t[64][65];
  const float* W = (blockIdx.z == 0) ? W0 : (blockIdx.z == 1) ? W1 : (blockIdx.z == 2) ? W2 : W3;
  u16* T = (blockIdx.z == 0) ? T0 : (blockIdx.z == 1) ? T1 : (blockIdx.z == 2) ? T2 : T3;
  int n0 = blockIdx.x * 64, k0 = blockIdx.y * 64;
  int x = threadIdx.x, y = threadIdx.y;
#pragma unroll
  for (int i = 0; i < 16; ++i)
    t[y + i * 4][x] = W[(size_t)(k0 + y + i * 4) * DM + n0 + x];
  __syncthreads();
#pragma unroll
  for (int i = 0; i < 16; ++i) {
    int n = y + i * 4;
    T[(size_t)(n0 + n) * DM + k0 + x] = f2bf(t[x][n]);
  }
}

// ---------------- 128x128 GEMM core (A[M][K] bf16, Bt[N][K] bf16, K=1024) ----
// LDS rows 128B (64 bf16), 8x16B slots, slot ^= (row&7) swizzle applied on the
// global SOURCE address (global_load_lds dest must be linear) and on reads.
DEV void gemm_main(const u16* __restrict__ A, const u16* __restrict__ Bt,
                   int mbase, int nbase, u16* sA, u16* sB, f32x4 (&acc)[4][4]) {
  const int tid = threadIdx.x;
  const int lane = tid & 63, w = tid >> 6;
  const int wm = w >> 1, wn = w & 1;
  const int srow = lane >> 3;                 // 0..7 row within 8-row stage
  const int sslot = (lane & 7) ^ srow;        // pre-swizzled 16B slot
  const int rA = lane & 15, ksl = lane >> 4;

  const u16* Ag = A + (size_t)(mbase + srow) * DM + sslot * 8;
  const u16* Bg = Bt + (size_t)(nbase + srow) * DM + sslot * 8;

  for (int kt = 0; kt < DM; kt += 64) {
    __syncthreads();
#pragma unroll
    for (int i = 0; i < 4; ++i) {
      int rloc = w * 32 + i * 8;              // wave stages rows [w*32, w*32+32)
      gld16(sA + rloc * 64, Ag + (size_t)rloc * DM + kt);
      gld16(sB + rloc * 64, Bg + (size_t)rloc * DM + kt);
    }
    __syncthreads();
    bf8v a[4][2], b[4][2];
#pragma unroll
    for (int mi = 0; mi < 4; ++mi)
#pragma unroll
      for (int kk = 0; kk < 2; ++kk) {
        int r = wm * 64 + mi * 16 + rA;
        a[mi][kk] = *(const bf8v*)(sA + r * 64 + (((kk * 4 + ksl) ^ (lane & 7)) * 8));
      }
#pragma unroll
    for (int nf = 0; nf < 4; ++nf)
#pragma unroll
      for (int kk = 0; kk < 2; ++kk) {
        int r = wn * 64 + nf * 16 + rA;
        b[nf][kk] = *(const bf8v*)(sB + r * 64 + (((kk * 4 + ksl) ^ (lane & 7)) * 8));
      }
#pragma unroll
    for (int kk = 0; kk < 2; ++kk)
#pragma unroll
      for (int mi = 0; mi < 4; ++mi)
#pragma unroll
        for (int nf = 0; nf < 4; ++nf)
          acc[mi][nf] = MFMA(a[mi][kk], b[nf][kk], acc[mi][nf]);
  }
}

// ---------------- QKV projection ----------------
__global__ __launch_bounds__(256, 2) void k_qkv(
    const u16* __restrict__ xb,
    const u16* __restrict__ wqT, const u16* __restrict__ wkT, const u16* __restrict__ wvT,
    const float* __restrict__ bq, const float* __restrict__ bk, const float* __restrict__ bv,
    u16* __restrict__ Q, u16* __restrict__ K, u16* __restrict__ VT) {
  __shared__ u16 sA[128 * 64], sB[128 * 64];
  const int mat = blockIdx.z;
  const u16* Bt = (mat == 0) ? wqT : (mat == 1) ? wkT : wvT;
  const float* bias = (mat == 0) ? bq : (mat == 1) ? bk : bv;
  const int mbase = blockIdx.y * 128, nbase = blockIdx.x * 128;

  f32x4 acc[4][4];
#pragma unroll
  for (int i = 0; i < 4; ++i)
#pragma unroll
    for (int j = 0; j < 4; ++j) acc[i][j] = (f32x4){0.f, 0.f, 0.f, 0.f};

  gemm_main(xb, Bt, mbase, nbase, sA, sB, acc);

  const int lane = threadIdx.x & 63, w = threadIdx.x >> 6;
  const int wm = w >> 1, wn = w & 1;
  const int ksl = lane >> 4, rA = lane & 15;
  const float scale = (mat == 0) ? 0.03125f : 1.0f;  // fold 1/sqrt(1024) into Q
#pragma unroll
  for (int nf = 0; nf < 4; ++nf) {
    const int n = nbase + wn * 64 + nf * 16 + rA;
    const float bb = bias[n];
    const int h = n >> 6, d = n & 63;
#pragma unroll
    for (int mi = 0; mi < 4; ++mi) {
      const int m0 = mbase + wm * 64 + mi * 16 + ksl * 4;
      const int b = m0 >> 11, s = m0 & 2047;
      if (mat == 2) {  // V stored transposed [b][h][d][s]; 4 consecutive s
        ushort4 ov;
        ov.x = f2bf(acc[mi][nf][0] + bb);
        ov.y = f2bf(acc[mi][nf][1] + bb);
        ov.z = f2bf(acc[mi][nf][2] + bb);
        ov.w = f2bf(acc[mi][nf][3] + bb);
        *(ushort4*)&VT[((size_t)(b * H_ + h) * D_ + d) * S_ + s] = ov;
      } else {         // Q/K stored [b][h][s][d]
        u16* dst = (mat == 0) ? Q : K;
#pragma unroll
        for (int reg = 0; reg < 4; ++reg) {
          float vq = (acc[mi][nf][reg] + bb) * scale;
          dst[((size_t)(b * H_ + h) * S_ + (s + reg)) * D_ + d] = f2bf(vq);
        }
      }
    }
  }
}

// ---------------- causal flash attention ----------------
__global__ __launch_bounds__(256, 2) void k_attn(
    const u16* __restrict__ Q, const u16* __restrict__ K, const u16* __restrict__ VT,
    u16* __restrict__ ctx) {
  __shared__ u16 sK[64 * 64], sV[64 * 64], sP[4][32 * 64];
  const int bh = blockIdx.y;
  const int q0 = blockIdx.x * 128;
  const int tid = threadIdx.x, lane = tid & 63, w = tid >> 6;
  const int rA = lane & 15, ksl = lane >> 4;
  const u16* Qh = Q + (size_t)bh * S_ * D_;
  const u16* Kh = K + (size_t)bh * S_ * D_;
  const u16* Vh = VT + (size_t)bh * D_ * S_;

  // Q fragments for this wave's 32 rows (scale already folded in)
  bf8v qf[2][2];
#pragma unroll
  for (int mi = 0; mi < 2; ++mi)
#pragma unroll
    for (int kk = 0; kk < 2; ++kk) {
      int q = q0 + w * 32 + mi * 16 + rA;
      qf[mi][kk] = *(const bf8v*)(Qh + (size_t)q * D_ + kk * 32 + ksl * 8);
    }

  f32x4 o[2][4];
  float mrow[2][4], lrow[2][4];
#pragma unroll
  for (int mi = 0; mi < 2; ++mi) {
#pragma unroll
    for (int nf = 0; nf < 4; ++nf) o[mi][nf] = (f32x4){0.f, 0.f, 0.f, 0.f};
#pragma unroll
    for (int reg = 0; reg < 4; ++reg) { mrow[mi][reg] = -INFINITY; lrow[mi][reg] = 0.f; }
  }

  const int qmin = q0 + w * 32;
  const int qmax = qmin + 31;
  const int nt = 2 * blockIdx.x + 2;   // KV tiles needed for causal coverage
  const int srow = lane >> 3;
  const int sslot = (lane & 7) ^ srow;
  u16* pw = sP[w];

  for (int t = 0; t < nt; ++t) {
    const int kv0 = t * 64;
    __syncthreads();
#pragma unroll
    for (int i = 0; i < 2; ++i) {
      int rl = w * 16 + i * 8;
      gld16(sK + rl * 64, Kh + (size_t)(kv0 + rl + srow) * D_ + sslot * 8);
      gld16(sV + rl * 64, Vh + (size_t)(rl + srow) * S_ + kv0 + sslot * 8);
    }
    __syncthreads();
    if (kv0 > qmax) continue;  // fully masked for this wave (barriers stay aligned)

    // S = Q K^T  [32 q][64 kv]
    f32x4 s[2][4];
#pragma unroll
    for (int mi = 0; mi < 2; ++mi)
#pragma unroll
      for (int nf = 0; nf < 4; ++nf) s[mi][nf] = (f32x4){0.f, 0.f, 0.f, 0.f};
#pragma unroll
    for (int nf = 0; nf < 4; ++nf)
#pragma unroll
      for (int kk = 0; kk < 2; ++kk) {
        int r = nf * 16 + rA;
        bf8v kf = *(const bf8v*)(sK + r * 64 + (((kk * 4 + ksl) ^ (lane & 7)) * 8));
#pragma unroll
        for (int mi = 0; mi < 2; ++mi)
          s[mi][nf] = MFMA(qf[mi][kk], kf, s[mi][nf]);
      }

    if (kv0 + 63 > qmin) {  // causal mask (elementwise only when tile straddles diag)
#pragma unroll
      for (int mi = 0; mi < 2; ++mi)
#pragma unroll
        for (int reg = 0; reg < 4; ++reg) {
          int q = qmin + mi * 16 + ksl * 4 + reg;
#pragma unroll
          for (int nf = 0; nf < 4; ++nf) {
            int kv = kv0 + nf * 16 + rA;
            if (kv > q) s[mi][nf][reg] = -INFINITY;
          }
        }
    }

    // online softmax; rows live across the 16 lanes sharing (lane>>4)
#pragma unroll
    for (int mi = 0; mi < 2; ++mi)
#pragma unroll
      for (int reg = 0; reg < 4; ++reg) {
        float mx = fmaxf(fmaxf(s[mi][0][reg], s[mi][1][reg]),
                         fmaxf(s[mi][2][reg], s[mi][3][reg]));
        mx = fmaxf(mx, __shfl_xor(mx, 1));
        mx = fmaxf(mx, __shfl_xor(mx, 2));
        mx = fmaxf(mx, __shfl_xor(mx, 4));
        mx = fmaxf(mx, __shfl_xor(mx, 8));
        float mnew = fmaxf(mrow[mi][reg], mx);
        float corr = __expf(mrow[mi][reg] - mnew);
        float ps = 0.f;
#pragma unroll
        for (int nf = 0; nf < 4; ++nf) {
          float p = __expf(s[mi][nf][reg] - mnew);
          s[mi][nf][reg] = p;
          ps += p;
        }
        ps += __shfl_xor(ps, 1);
        ps += __shfl_xor(ps, 2);
        ps += __shfl_xor(ps, 4);
        ps += __shfl_xor(ps, 8);
        lrow[mi][reg] = lrow[mi][reg] * corr + ps;
        mrow[mi][reg] = mnew;
#pragma unroll
        for (int nf = 0; nf < 4; ++nf) o[mi][nf][reg] *= corr;
      }

    // P -> per-wave LDS (swizzled), re-read as MFMA A-fragment
#pragma unroll
    for (int mi = 0; mi < 2; ++mi)
#pragma unroll
      for (int reg = 0; reg < 4; ++reg) {
        int qr = mi * 16 + ksl * 4 + reg;
#pragma unroll
        for (int nf = 0; nf < 4; ++nf) {
          int kv = nf * 16 + rA;
          pw[qr * 64 + (((kv >> 3) ^ (qr & 7)) * 8) + (kv & 7)] = f2bf(s[mi][nf][reg]);
        }
      }

#pragma unroll
    for (int kk = 0; kk < 2; ++kk) {
      bf8v pf[2], vf[4];
#pragma unroll
      for (int mi = 0; mi < 2; ++mi) {
        int qr = mi * 16 + rA;
        pf[mi] = *(const bf8v*)(pw + qr * 64 + (((kk * 4 + ksl) ^ (qr & 7)) * 8));
      }
#pragma unroll
      for (int nf = 0; nf < 4; ++nf) {
        int d = nf * 16 + rA;
        vf[nf] = *(const bf8v*)(sV + d * 64 + (((kk * 4 + ksl) ^ (d & 7)) * 8));
      }
#pragma unroll
      for (int mi = 0; mi < 2; ++mi)
#pragma unroll
        for (int nf = 0; nf < 4; ++nf)
          o[mi][nf] = MFMA(pf[mi], vf[nf], o[mi][nf]);
    }
  }

  // epilogue: O/l -> ctx [b][s][h*64+d] bf16
  const int b = bh >> 4, h = bh & 15;
#pragma unroll
  for (int mi = 0; mi < 2; ++mi)
#pragma unroll
    for (int reg = 0; reg < 4; ++reg) {
      float inv = 1.f / lrow[mi][reg];
      int q = qmin + mi * 16 + ksl * 4 + reg;
#pragma unroll
      for (int nf = 0; nf < 4; ++nf) {
        int d = nf * 16 + rA;
        ctx[((size_t)b * S_ + q) * DM + h * 64 + d] = f2bf(o[mi][nf][reg] * inv);
      }
    }
}

// ---------------- output projection (fp32 out) ----------------
__global__ __launch_bounds__(256, 2) void k_oproj(
    const u16* __restrict__ ctx, const u16* __restrict__ woT,
    const float* __restrict__ bo, float* __restrict__ out) {
  __shared__ u16 sA[128 * 64], sB[128 * 64];
  const int mbase = blockIdx.y * 128, nbase = blockIdx.x * 128;
  f32x4 acc[4][4];
#pragma unroll
  for (int i = 0; i < 4; ++i)
#pragma unroll
    for (int j = 0; j < 4; ++j) acc[i][j] = (f32x4){0.f, 0.f, 0.f, 0.f};

  gemm_main(ctx, woT, mbase, nbase, sA, sB, acc);

  const int lane = threadIdx.x & 63, w = threadIdx.x >> 6;
  const int wm = w >> 1, wn = w & 1;
  const int ksl = lane >> 4, rA = lane & 15;
#pragma unroll
  for (int nf = 0; nf < 4; ++nf) {
    const int n = nbase + wn * 64 + nf * 16 + rA;
    const float bb = bo[n];
#pragma unroll
    for (int mi = 0; mi < 4; ++mi) {
      const int m0 = mbase + wm * 64 + mi * 16 + ksl * 4;
#pragma unroll
      for (int reg = 0; reg < 4; ++reg)
        out[(size_t)(m0 + reg) * DM + n] = acc[mi][nf][reg] + bb;
    }
  }
}

extern "C" void kernel_launch(void* const* d_in, const int* in_sizes, int n_in,
                              void* d_out, int out_size, void* d_ws, size_t ws_size,
                              hipStream_t stream) {
  const float* x  = (const float*)d_in[0];
  const float* Wq = (const float*)d_in[1];
  const float* bq = (const float*)d_in[2];
  const float* Wk = (const float*)d_in[3];
  const float* bk = (const float*)d_in[4];
  const float* Wv = (const float*)d_in[5];
  const float* bv = (const float*)d_in[6];
  const float* Wo = (const float*)d_in[7];
  const float* bo = (const float*)d_in[8];
  float* out = (float*)d_out;

  char* ws = (char*)d_ws;
  // layout (MB): [0,16) xb (later reused as ctx), [16,24) W^T x4,
  // [24,40) Q, [40,56) K, [56,72) V^T  -> 72 MB total
  u16* xb  = (u16*)(ws);
  u16* wqT = (u16*)(ws + (size_t)(16u << 20));
  u16* wkT = (u16*)(ws + (size_t)(18u << 20));
  u16* wvT = (u16*)(ws + (size_t)(20u << 20));
  u16* woT = (u16*)(ws + (size_t)(22u << 20));
  u16* Qd  = (u16*)(ws + (size_t)(24u << 20));
  u16* Kd  = (u16*)(ws + (size_t)(40u << 20));
  u16* VTd = (u16*)(ws + (size_t)(56u << 20));
  u16* ctx = xb;  // xb dead after k_qkv; stream-ordered reuse

  k_cvt_x<<<2048, 256, 0, stream>>>(x, xb, (8192 * 1024) / 4);
  k_cvt_wT4<<<dim3(16, 16, 4), dim3(64, 4), 0, stream>>>(Wq, Wk, Wv, Wo, wqT, wkT, wvT, woT);
  k_qkv<<<dim3(8, 64, 3), 256, 0, stream>>>(xb, wqT, wkT, wvT, bq, bk, bv, Qd, Kd, VTd);
  k_attn<<<dim3(16, 64), 256, 0, stream>>>(Qd, Kd, VTd, ctx);
  k_oproj<<<dim3(8, 64), 256, 0, stream>>>(ctx, woT, bo, out);
}

// Round 2
// 376.964 us; speedup vs baseline: 1.1085x; 1.1085x over previous
//
#include <hip/hip_runtime.h>
#include <hip/hip_bf16.h>
#include <math.h>

typedef short bf8v __attribute__((ext_vector_type(8)));   // 8 bf16 (4 VGPRs)
typedef float f32x4 __attribute__((ext_vector_type(4)));
typedef unsigned short u16;
typedef unsigned int u32;

#define DEV __device__ __forceinline__

static constexpr int S_ = 2048;
static constexpr int H_ = 16;
static constexpr int D_ = 64;
static constexpr int DM = 1024;

DEV u16 f2bf(float f) {
  union { float f; u32 u; } v; v.f = f;
  return (u16)((v.u + 0x7fffu + ((v.u >> 16) & 1u)) >> 16);  // RNE
}

DEV void gld16(u16* lds, const u16* g) {
  __builtin_amdgcn_global_load_lds(
      (const __attribute__((address_space(1))) u32*)g,
      (__attribute__((address_space(3))) u32*)lds, 16, 0, 0);
}

DEV f32x4 MFMA(bf8v a, bf8v b, f32x4 c) {
  return __builtin_amdgcn_mfma_f32_16x16x32_bf16(a, b, c, 0, 0, 0);
}

// ---------------- converts ----------------
__global__ void k_cvt_x(const float* __restrict__ x, u16* __restrict__ xb, int n4) {
  int i = blockIdx.x * blockDim.x + threadIdx.x;
  int stride = gridDim.x * blockDim.x;
  for (; i < n4; i += stride) {
    float4 v = ((const float4*)x)[i];
    ushort4 o;
    o.x = f2bf(v.x); o.y = f2bf(v.y); o.z = f2bf(v.z); o.w = f2bf(v.w);
    ((ushort4*)xb)[i] = o;
  }
}

// W [K][N] f32 -> WT [N][K] bf16, 64x64 LDS tile transpose; z selects matrix
__global__ void k_cvt_wT4(const float* __restrict__ W0, const float* __restrict__ W1,
                          const float* __restrict__ W2, const float* __restrict__ W3,
                          u16* __restrict__ T0, u16* __restrict__ T1,
                          u16* __restrict__ T2, u16* __restrict__ T3) {
  __shared__ float t[64][65];
  const float* W = (blockIdx.z == 0) ? W0 : (blockIdx.z == 1) ? W1 : (blockIdx.z == 2) ? W2 : W3;
  u16* T = (blockIdx.z == 0) ? T0 : (blockIdx.z == 1) ? T1 : (blockIdx.z == 2) ? T2 : T3;
  int n0 = blockIdx.x * 64, k0 = blockIdx.y * 64;
  int x = threadIdx.x, y = threadIdx.y;
#pragma unroll
  for (int i = 0; i < 16; ++i)
    t[y + i * 4][x] = W[(size_t)(k0 + y + i * 4) * DM + n0 + x];
  __syncthreads();
#pragma unroll
  for (int i = 0; i < 16; ++i) {
    int n = y + i * 4;
    T[(size_t)(n0 + n) * DM + k0 + x] = f2bf(t[x][n]);
  }
}

// ---------------- 128x128 GEMM core (A[M][K] bf16, Bt[N][K] bf16, K=1024) ----
DEV void gemm_main(const u16* __restrict__ A, const u16* __restrict__ Bt,
                   int mbase, int nbase, u16* sA, u16* sB, f32x4 (&acc)[4][4]) {
  const int tid = threadIdx.x;
  const int lane = tid & 63, w = tid >> 6;
  const int wm = w >> 1, wn = w & 1;
  const int srow = lane >> 3;                 // 0..7 row within 8-row stage
  const int sslot = (lane & 7) ^ srow;        // pre-swizzled 16B slot
  const int rA = lane & 15, ksl = lane >> 4;

  const u16* Ag = A + (size_t)(mbase + srow) * DM + sslot * 8;
  const u16* Bg = Bt + (size_t)(nbase + srow) * DM + sslot * 8;

  for (int kt = 0; kt < DM; kt += 64) {
    __syncthreads();
#pragma unroll
    for (int i = 0; i < 4; ++i) {
      int rloc = w * 32 + i * 8;              // wave stages rows [w*32, w*32+32)
      gld16(sA + rloc * 64, Ag + (size_t)rloc * DM + kt);
      gld16(sB + rloc * 64, Bg + (size_t)rloc * DM + kt);
    }
    __syncthreads();
    bf8v a[4][2], b[4][2];
#pragma unroll
    for (int mi = 0; mi < 4; ++mi)
#pragma unroll
      for (int kk = 0; kk < 2; ++kk) {
        int r = wm * 64 + mi * 16 + rA;
        a[mi][kk] = *(const bf8v*)(sA + r * 64 + (((kk * 4 + ksl) ^ (lane & 7)) * 8));
      }
#pragma unroll
    for (int nf = 0; nf < 4; ++nf)
#pragma unroll
      for (int kk = 0; kk < 2; ++kk) {
        int r = wn * 64 + nf * 16 + rA;
        b[nf][kk] = *(const bf8v*)(sB + r * 64 + (((kk * 4 + ksl) ^ (lane & 7)) * 8));
      }
#pragma unroll
    for (int kk = 0; kk < 2; ++kk)
#pragma unroll
      for (int mi = 0; mi < 4; ++mi)
#pragma unroll
        for (int nf = 0; nf < 4; ++nf)
          acc[mi][nf] = MFMA(a[mi][kk], b[nf][kk], acc[mi][nf]);
  }
}

// ---------------- QKV projection ----------------
__global__ __launch_bounds__(256, 2) void k_qkv(
    const u16* __restrict__ xb,
    const u16* __restrict__ wqT, const u16* __restrict__ wkT, const u16* __restrict__ wvT,
    const float* __restrict__ bq, const float* __restrict__ bk, const float* __restrict__ bv,
    u16* __restrict__ Q, u16* __restrict__ K, u16* __restrict__ VT) {
  __shared__ u16 sA[128 * 64], sB[128 * 64];
  const int mat = blockIdx.z;
  const u16* Bt = (mat == 0) ? wqT : (mat == 1) ? wkT : wvT;
  const float* bias = (mat == 0) ? bq : (mat == 1) ? bk : bv;
  const int mbase = blockIdx.y * 128, nbase = blockIdx.x * 128;

  f32x4 acc[4][4];
#pragma unroll
  for (int i = 0; i < 4; ++i)
#pragma unroll
    for (int j = 0; j < 4; ++j) acc[i][j] = (f32x4){0.f, 0.f, 0.f, 0.f};

  gemm_main(xb, Bt, mbase, nbase, sA, sB, acc);

  const int lane = threadIdx.x & 63, w = threadIdx.x >> 6;
  const int wm = w >> 1, wn = w & 1;
  const int ksl = lane >> 4, rA = lane & 15;
  const float scale = (mat == 0) ? 0.03125f : 1.0f;  // fold 1/sqrt(1024) into Q
#pragma unroll
  for (int nf = 0; nf < 4; ++nf) {
    const int n = nbase + wn * 64 + nf * 16 + rA;
    const float bb = bias[n];
    const int h = n >> 6, d = n & 63;
#pragma unroll
    for (int mi = 0; mi < 4; ++mi) {
      const int m0 = mbase + wm * 64 + mi * 16 + ksl * 4;
      const int b = m0 >> 11, s = m0 & 2047;
      if (mat == 2) {  // V stored transposed [b][h][d][s]; 4 consecutive s
        ushort4 ov;
        ov.x = f2bf(acc[mi][nf][0] + bb);
        ov.y = f2bf(acc[mi][nf][1] + bb);
        ov.z = f2bf(acc[mi][nf][2] + bb);
        ov.w = f2bf(acc[mi][nf][3] + bb);
        *(ushort4*)&VT[((size_t)(b * H_ + h) * D_ + d) * S_ + s] = ov;
      } else {         // Q/K stored [b][h][s][d]
        u16* dst = (mat == 0) ? Q : K;
#pragma unroll
        for (int reg = 0; reg < 4; ++reg) {
          float vq = (acc[mi][nf][reg] + bb) * scale;
          dst[((size_t)(b * H_ + h) * S_ + (s + reg)) * D_ + d] = f2bf(vq);
        }
      }
    }
  }
}

// ---------------- causal flash attention (barrier-free, swapped QK^T) -------
// Per wave: 32 q rows. S^T = K*Q^T so each lane owns ONE q column (q=lane&15
// +16*mi) -> softmax stats lane-local (2 shfl_xor per reduce). O accumulated
// as O^T = V^T*P^T (C col = q = lane&15, same domain -> rescale is in-lane).
// K/V fragments load DIRECTLY from global (L1/L2-resident tiles, no LDS
// staging, no __syncthreads). P goes through per-wave swizzled LDS.
__global__ __launch_bounds__(256, 2) void k_attn(
    const u16* __restrict__ Q, const u16* __restrict__ K, const u16* __restrict__ VT,
    u16* __restrict__ ctx) {
  __shared__ u16 sP[4][32 * 64];  // per-wave P buffer, XOR-swizzled 16B slots
  const int g = blockIdx.x;
  // XCD grouping: g%8 -> XCD; each XCD handles 8 consecutive bh (1MB KV set).
  const int bh = (g & 7) * 8 + ((g >> 3) >> 4);
  const int qi = 15 - ((g >> 3) & 15);        // heavy q-chunks first
  const int tid = threadIdx.x, lane = tid & 63, w = tid >> 6;
  const int col = lane & 15, grp = lane >> 4;
  const int qmin = qi * 128 + w * 32;
  const u16* Qh = Q + (size_t)bh * S_ * D_;
  const u16* Kh = K + (size_t)bh * S_ * D_;
  const u16* Vh = VT + (size_t)bh * D_ * S_;
  u16* pw = sP[w];

  // Q fragments (B-operand of S^T): lane holds Q[q=col+16mi][d=grp*8..]
  bf8v qf[2][2];
#pragma unroll
  for (int mi = 0; mi < 2; ++mi)
#pragma unroll
    for (int kk = 0; kk < 2; ++kk)
      qf[mi][kk] = *(const bf8v*)(Qh + (size_t)(qmin + mi * 16 + col) * D_ + kk * 32 + grp * 8);

  f32x4 o[2][4];
#pragma unroll
  for (int mi = 0; mi < 2; ++mi)
#pragma unroll
    for (int nf = 0; nf < 4; ++nf) o[mi][nf] = (f32x4){0.f, 0.f, 0.f, 0.f};
  float mrow[2] = {-INFINITY, -INFINITY};
  float lrow[2] = {0.f, 0.f};

  const int nt = (qmin >> 6) + 1;
  for (int t = 0; t < nt; ++t) {
    const int kv0 = t * 64;
    // K fragments (A-operand): lane holds K[kv=kv0+nf*16+col][d=kk*32+grp*8..]
    bf8v kf[4][2];
#pragma unroll
    for (int nf = 0; nf < 4; ++nf)
#pragma unroll
      for (int kk = 0; kk < 2; ++kk)
        kf[nf][kk] = *(const bf8v*)(Kh + (size_t)(kv0 + nf * 16 + col) * D_ + kk * 32 + grp * 8);

    f32x4 st[2][4];
#pragma unroll
    for (int mi = 0; mi < 2; ++mi)
#pragma unroll
      for (int nf = 0; nf < 4; ++nf) st[mi][nf] = (f32x4){0.f, 0.f, 0.f, 0.f};

    __builtin_amdgcn_s_setprio(1);
#pragma unroll
    for (int kk = 0; kk < 2; ++kk)
#pragma unroll
      for (int nf = 0; nf < 4; ++nf)
#pragma unroll
        for (int mi = 0; mi < 2; ++mi)
          st[mi][nf] = MFMA(kf[nf][kk], qf[mi][kk], st[mi][nf]);
    __builtin_amdgcn_s_setprio(0);

    // V^T fragments (A-operand of PV): issue early to hide L2 latency under
    // softmax VALU. lane holds VT[d=nf*16+col][s=kv0+kk*32+grp*8..]
    bf8v vf[4][2];
#pragma unroll
    for (int nf = 0; nf < 4; ++nf)
#pragma unroll
      for (int kk = 0; kk < 2; ++kk)
        vf[nf][kk] = *(const bf8v*)(Vh + (size_t)(nf * 16 + col) * S_ + kv0 + kk * 32 + grp * 8);

    if (t == nt - 1) {  // causal mask: only the diagonal tile straddles
#pragma unroll
      for (int mi = 0; mi < 2; ++mi) {
        const int q = qmin + mi * 16 + col;
#pragma unroll
        for (int nf = 0; nf < 4; ++nf)
#pragma unroll
          for (int reg = 0; reg < 4; ++reg) {
            int kv = kv0 + nf * 16 + grp * 4 + reg;
            if (kv > q) st[mi][nf][reg] = -INFINITY;
          }
      }
    }

    // online softmax: lane owns q=col+16mi; 16 in-lane values + 2 shfl
#pragma unroll
    for (int mi = 0; mi < 2; ++mi) {
      float tm = st[mi][0][0];
#pragma unroll
      for (int nf = 0; nf < 4; ++nf) {
        tm = fmaxf(tm, fmaxf(fmaxf(st[mi][nf][0], st[mi][nf][1]),
                             fmaxf(st[mi][nf][2], st[mi][nf][3])));
      }
      tm = fmaxf(tm, __shfl_xor(tm, 16));
      tm = fmaxf(tm, __shfl_xor(tm, 32));
      float mnew = fmaxf(mrow[mi], tm);
      float corr = __expf(mrow[mi] - mnew);
      float ps = 0.f;
#pragma unroll
      for (int nf = 0; nf < 4; ++nf)
#pragma unroll
        for (int reg = 0; reg < 4; ++reg) {
          float p = __expf(st[mi][nf][reg] - mnew);
          st[mi][nf][reg] = p;
          ps += p;
        }
      ps += __shfl_xor(ps, 16);
      ps += __shfl_xor(ps, 32);
      lrow[mi] = lrow[mi] * corr + ps;
      mrow[mi] = mnew;
#pragma unroll
      for (int nf = 0; nf < 4; ++nf) o[mi][nf] *= corr;

      // P write: lane holds P[q][kv=nf*16+grp*4+reg] -> 4 consecutive kv
      const int q32 = mi * 16 + col;
#pragma unroll
      for (int nf = 0; nf < 4; ++nf) {
        ushort4 pv;
        pv.x = f2bf(st[mi][nf][0]);
        pv.y = f2bf(st[mi][nf][1]);
        pv.z = f2bf(st[mi][nf][2]);
        pv.w = f2bf(st[mi][nf][3]);
        const int slot = (nf * 2 + (grp >> 1)) ^ (q32 & 7);
        *(ushort4*)(pw + q32 * 64 + slot * 8 + (grp & 1) * 4) = pv;
      }
    }

    // P read (B-operand): lane needs P[q=col+16mi][kv=kk*32+grp*8..] (b128)
    bf8v pf[2][2];
#pragma unroll
    for (int mi = 0; mi < 2; ++mi) {
      const int q32 = mi * 16 + col;
#pragma unroll
      for (int kk = 0; kk < 2; ++kk) {
        const int slot = (kk * 4 + grp) ^ (q32 & 7);
        pf[mi][kk] = *(const bf8v*)(pw + q32 * 64 + slot * 8);
      }
    }

    __builtin_amdgcn_s_setprio(1);
#pragma unroll
    for (int kk = 0; kk < 2; ++kk)
#pragma unroll
      for (int nf = 0; nf < 4; ++nf)
#pragma unroll
        for (int mi = 0; mi < 2; ++mi)
          o[mi][nf] = MFMA(vf[nf][kk], pf[mi][kk], o[mi][nf]);
    __builtin_amdgcn_s_setprio(0);
  }

  // epilogue: O^T layout col q = col+16mi, row d = nf*16+grp*4+reg
  const int b = bh >> 4, h = bh & 15;
#pragma unroll
  for (int mi = 0; mi < 2; ++mi) {
    const float inv = 1.f / lrow[mi];
    const int q = qmin + mi * 16 + col;
#pragma unroll
    for (int nf = 0; nf < 4; ++nf) {
      ushort4 ov;
      ov.x = f2bf(o[mi][nf][0] * inv);
      ov.y = f2bf(o[mi][nf][1] * inv);
      ov.z = f2bf(o[mi][nf][2] * inv);
      ov.w = f2bf(o[mi][nf][3] * inv);
      *(ushort4*)&ctx[((size_t)b * S_ + q) * DM + h * 64 + nf * 16 + grp * 4] = ov;
    }
  }
}

// ---------------- output projection (fp32 out) ----------------
__global__ __launch_bounds__(256, 2) void k_oproj(
    const u16* __restrict__ ctx, const u16* __restrict__ woT,
    const float* __restrict__ bo, float* __restrict__ out) {
  __shared__ u16 sA[128 * 64], sB[128 * 64];
  const int mbase = blockIdx.y * 128, nbase = blockIdx.x * 128;
  f32x4 acc[4][4];
#pragma unroll
  for (int i = 0; i < 4; ++i)
#pragma unroll
    for (int j = 0; j < 4; ++j) acc[i][j] = (f32x4){0.f, 0.f, 0.f, 0.f};

  gemm_main(ctx, woT, mbase, nbase, sA, sB, acc);

  const int lane = threadIdx.x & 63, w = threadIdx.x >> 6;
  const int wm = w >> 1, wn = w & 1;
  const int ksl = lane >> 4, rA = lane & 15;
#pragma unroll
  for (int nf = 0; nf < 4; ++nf) {
    const int n = nbase + wn * 64 + nf * 16 + rA;
    const float bb = bo[n];
#pragma unroll
    for (int mi = 0; mi < 4; ++mi) {
      const int m0 = mbase + wm * 64 + mi * 16 + ksl * 4;
#pragma unroll
      for (int reg = 0; reg < 4; ++reg)
        out[(size_t)(m0 + reg) * DM + n] = acc[mi][nf][reg] + bb;
    }
  }
}

extern "C" void kernel_launch(void* const* d_in, const int* in_sizes, int n_in,
                              void* d_out, int out_size, void* d_ws, size_t ws_size,
                              hipStream_t stream) {
  const float* x  = (const float*)d_in[0];
  const float* Wq = (const float*)d_in[1];
  const float* bq = (const float*)d_in[2];
  const float* Wk = (const float*)d_in[3];
  const float* bk = (const float*)d_in[4];
  const float* Wv = (const float*)d_in[5];
  const float* bv = (const float*)d_in[6];
  const float* Wo = (const float*)d_in[7];
  const float* bo = (const float*)d_in[8];
  float* out = (float*)d_out;

  char* ws = (char*)d_ws;
  u16* xb  = (u16*)(ws);
  u16* wqT = (u16*)(ws + (size_t)(16u << 20));
  u16* wkT = (u16*)(ws + (size_t)(18u << 20));
  u16* wvT = (u16*)(ws + (size_t)(20u << 20));
  u16* woT = (u16*)(ws + (size_t)(22u << 20));
  u16* Qd  = (u16*)(ws + (size_t)(24u << 20));
  u16* Kd  = (u16*)(ws + (size_t)(40u << 20));
  u16* VTd = (u16*)(ws + (size_t)(56u << 20));
  u16* ctx = xb;  // xb dead after k_qkv; stream-ordered reuse

  k_cvt_x<<<2048, 256, 0, stream>>>(x, xb, (8192 * 1024) / 4);
  k_cvt_wT4<<<dim3(16, 16, 4), dim3(64, 4), 0, stream>>>(Wq, Wk, Wv, Wo, wqT, wkT, wvT, woT);
  k_qkv<<<dim3(8, 64, 3), 256, 0, stream>>>(xb, wqT, wkT, wvT, bq, bk, bv, Qd, Kd, VTd);
  k_attn<<<1024, 256, 0, stream>>>(Qd, Kd, VTd, ctx);
  k_oproj<<<dim3(8, 64), 256, 0, stream>>>(ctx, woT, bo, out);
}

// Round 6
// 317.853 us; speedup vs baseline: 1.3146x; 1.1860x over previous
//
#include <hip/hip_runtime.h>
#include <hip/hip_bf16.h>
#include <math.h>

typedef short bf8v __attribute__((ext_vector_type(8)));   // 8 bf16 (4 VGPRs)
typedef float f32x4 __attribute__((ext_vector_type(4)));
typedef unsigned short u16;
typedef unsigned int u32;

#define DEV __device__ __forceinline__

static constexpr int S_ = 2048;
static constexpr int H_ = 16;
static constexpr int D_ = 64;
static constexpr int DM = 1024;

DEV u16 f2bf(float f) {
  union { float f; u32 u; } v; v.f = f;
  return (u16)((v.u + 0x7fffu + ((v.u >> 16) & 1u)) >> 16);  // RNE
}

DEV void gld16(u16* lds, const u16* g) {
  __builtin_amdgcn_global_load_lds(
      (const __attribute__((address_space(1))) u32*)g,
      (__attribute__((address_space(3))) u32*)lds, 16, 0, 0);
}

DEV f32x4 MFMA(bf8v a, bf8v b, f32x4 c) {
  return __builtin_amdgcn_mfma_f32_16x16x32_bf16(a, b, c, 0, 0, 0);
}

// ---------------- converts ----------------
__global__ void k_cvt_x(const float* __restrict__ x, u16* __restrict__ xb, int n4) {
  int i = blockIdx.x * blockDim.x + threadIdx.x;
  int stride = gridDim.x * blockDim.x;
  for (; i < n4; i += stride) {
    float4 v = ((const float4*)x)[i];
    ushort4 o;
    o.x = f2bf(v.x); o.y = f2bf(v.y); o.z = f2bf(v.z); o.w = f2bf(v.w);
    ((ushort4*)xb)[i] = o;
  }
}

// W [K][N] f32 -> WT [N][K] bf16, 64x64 LDS tile transpose; z selects matrix
__global__ void k_cvt_wT4(const float* __restrict__ W0, const float* __restrict__ W1,
                          const float* __restrict__ W2, const float* __restrict__ W3,
                          u16* __restrict__ T0, u16* __restrict__ T1,
                          u16* __restrict__ T2, u16* __restrict__ T3) {
  __shared__ float t[64][65];
  const float* W = (blockIdx.z == 0) ? W0 : (blockIdx.z == 1) ? W1 : (blockIdx.z == 2) ? W2 : W3;
  u16* T = (blockIdx.z == 0) ? T0 : (blockIdx.z == 1) ? T1 : (blockIdx.z == 2) ? T2 : T3;
  int n0 = blockIdx.x * 64, k0 = blockIdx.y * 64;
  int x = threadIdx.x, y = threadIdx.y;
#pragma unroll
  for (int i = 0; i < 16; ++i)
    t[y + i * 4][x] = W[(size_t)(k0 + y + i * 4) * DM + n0 + x];
  __syncthreads();
#pragma unroll
  for (int i = 0; i < 16; ++i) {
    int n = y + i * 4;
    T[(size_t)(n0 + n) * DM + k0 + x] = f2bf(t[x][n]);
  }
}

// ---------------- 128x128 GEMM core (A[M][K] bf16, Bt[N][K] bf16, K=1024) ----
DEV void gemm_main(const u16* __restrict__ A, const u16* __restrict__ Bt,
                   int mbase, int nbase, u16* sA, u16* sB, f32x4 (&acc)[4][4]) {
  const int tid = threadIdx.x;
  const int lane = tid & 63, w = tid >> 6;
  const int wm = w >> 1, wn = w & 1;
  const int srow = lane >> 3;                 // 0..7 row within 8-row stage
  const int sslot = (lane & 7) ^ srow;        // pre-swizzled 16B slot
  const int rA = lane & 15, ksl = lane >> 4;

  const u16* Ag = A + (size_t)(mbase + srow) * DM + sslot * 8;
  const u16* Bg = Bt + (size_t)(nbase + srow) * DM + sslot * 8;

  for (int kt = 0; kt < DM; kt += 64) {
    __syncthreads();
#pragma unroll
    for (int i = 0; i < 4; ++i) {
      int rloc = w * 32 + i * 8;              // wave stages rows [w*32, w*32+32)
      gld16(sA + rloc * 64, Ag + (size_t)rloc * DM + kt);
      gld16(sB + rloc * 64, Bg + (size_t)rloc * DM + kt);
    }
    __syncthreads();
    bf8v a[4][2], b[4][2];
#pragma unroll
    for (int mi = 0; mi < 4; ++mi)
#pragma unroll
      for (int kk = 0; kk < 2; ++kk) {
        int r = wm * 64 + mi * 16 + rA;
        a[mi][kk] = *(const bf8v*)(sA + r * 64 + (((kk * 4 + ksl) ^ (lane & 7)) * 8));
      }
#pragma unroll
    for (int nf = 0; nf < 4; ++nf)
#pragma unroll
      for (int kk = 0; kk < 2; ++kk) {
        int r = wn * 64 + nf * 16 + rA;
        b[nf][kk] = *(const bf8v*)(sB + r * 64 + (((kk * 4 + ksl) ^ (lane & 7)) * 8));
      }
#pragma unroll
    for (int kk = 0; kk < 2; ++kk)
#pragma unroll
      for (int mi = 0; mi < 4; ++mi)
#pragma unroll
        for (int nf = 0; nf < 4; ++nf)
          acc[mi][nf] = MFMA(a[mi][kk], b[nf][kk], acc[mi][nf]);
  }
}

// ---------------- QKV projection ----------------
__global__ __launch_bounds__(256, 2) void k_qkv(
    const u16* __restrict__ xb,
    const u16* __restrict__ wqT, const u16* __restrict__ wkT, const u16* __restrict__ wvT,
    const float* __restrict__ bq, const float* __restrict__ bk, const float* __restrict__ bv,
    u16* __restrict__ Q, u16* __restrict__ K, u16* __restrict__ VT) {
  __shared__ u16 sA[128 * 64], sB[128 * 64];
  const int mat = blockIdx.z;
  const u16* Bt = (mat == 0) ? wqT : (mat == 1) ? wkT : wvT;
  const float* bias = (mat == 0) ? bq : (mat == 1) ? bk : bv;
  const int mbase = blockIdx.y * 128, nbase = blockIdx.x * 128;

  f32x4 acc[4][4];
#pragma unroll
  for (int i = 0; i < 4; ++i)
#pragma unroll
    for (int j = 0; j < 4; ++j) acc[i][j] = (f32x4){0.f, 0.f, 0.f, 0.f};

  gemm_main(xb, Bt, mbase, nbase, sA, sB, acc);

  const int lane = threadIdx.x & 63, w = threadIdx.x >> 6;
  const int wm = w >> 1, wn = w & 1;
  const int ksl = lane >> 4, rA = lane & 15;
  const float scale = (mat == 0) ? 0.03125f : 1.0f;  // fold 1/sqrt(1024) into Q
#pragma unroll
  for (int nf = 0; nf < 4; ++nf) {
    const int n = nbase + wn * 64 + nf * 16 + rA;
    const float bb = bias[n];
    const int h = n >> 6, d = n & 63;
#pragma unroll
    for (int mi = 0; mi < 4; ++mi) {
      const int m0 = mbase + wm * 64 + mi * 16 + ksl * 4;
      const int b = m0 >> 11, s = m0 & 2047;
      if (mat == 2) {  // V stored transposed [b][h][d][s]; 4 consecutive s
        ushort4 ov;
        ov.x = f2bf(acc[mi][nf][0] + bb);
        ov.y = f2bf(acc[mi][nf][1] + bb);
        ov.z = f2bf(acc[mi][nf][2] + bb);
        ov.w = f2bf(acc[mi][nf][3] + bb);
        *(ushort4*)&VT[((size_t)(b * H_ + h) * D_ + d) * S_ + s] = ov;
      } else {         // Q/K stored [b][h][s][d]
        u16* dst = (mat == 0) ? Q : K;
#pragma unroll
        for (int reg = 0; reg < 4; ++reg) {
          float vq = (acc[mi][nf][reg] + bb) * scale;
          dst[((size_t)(b * H_ + h) * S_ + (s + reg)) * D_ + d] = f2bf(vq);
        }
      }
    }
  }
}

// ---------------- causal flash attention (barrier-free, swapped QK^T) -------
// One wave = one q-chunk job of 32 rows. S^T = K*Q^T: lane owns q=col+16mi;
// softmax stats lane-local (2 shfl). O^T = V^T*P^T, same lane domain.
// K/V fragments read directly from global (L1/L2-resident). K for tile t+1 is
// re-issued right after the QK MFMAs consume kf, hiding L2 latency under
// softmax+PV. Each wave runs the balanced pair (p, 63-p): constant 33 tiles.
DEV void attn_job(const u16* __restrict__ Qh, const u16* __restrict__ Kh,
                  const u16* __restrict__ Vh, u16* __restrict__ ctxh,
                  int qmin, u16* pw, int col, int grp) {
  // Q fragments (B-operand of S^T): lane holds Q[q=qmin+col+16mi][d=grp*8..]
  bf8v qf[2][2];
#pragma unroll
  for (int mi = 0; mi < 2; ++mi)
#pragma unroll
    for (int kk = 0; kk < 2; ++kk)
      qf[mi][kk] = *(const bf8v*)(Qh + (size_t)(qmin + mi * 16 + col) * D_ + kk * 32 + grp * 8);

  f32x4 o[2][4];
#pragma unroll
  for (int mi = 0; mi < 2; ++mi)
#pragma unroll
    for (int nf = 0; nf < 4; ++nf) o[mi][nf] = (f32x4){0.f, 0.f, 0.f, 0.f};
  float mrow[2] = {-INFINITY, -INFINITY};
  float lrow[2] = {0.f, 0.f};

  const int nt = (qmin >> 6) + 1;

  // prologue: K fragments for tile 0
  bf8v kf[4][2];
#pragma unroll
  for (int nf = 0; nf < 4; ++nf)
#pragma unroll
    for (int kk = 0; kk < 2; ++kk)
      kf[nf][kk] = *(const bf8v*)(Kh + (size_t)(nf * 16 + col) * D_ + kk * 32 + grp * 8);

  for (int t = 0; t < nt; ++t) {
    const int kv0 = t * 64;
    // V fragments for tile t (issued before QK; consumed by PV)
    bf8v vf[4][2];
#pragma unroll
    for (int nf = 0; nf < 4; ++nf)
#pragma unroll
      for (int kk = 0; kk < 2; ++kk)
        vf[nf][kk] = *(const bf8v*)(Vh + (size_t)(nf * 16 + col) * S_ + kv0 + kk * 32 + grp * 8);

    f32x4 st[2][4];
#pragma unroll
    for (int mi = 0; mi < 2; ++mi)
#pragma unroll
      for (int nf = 0; nf < 4; ++nf) st[mi][nf] = (f32x4){0.f, 0.f, 0.f, 0.f};

    __builtin_amdgcn_s_setprio(1);
#pragma unroll
    for (int kk = 0; kk < 2; ++kk)
#pragma unroll
      for (int nf = 0; nf < 4; ++nf)
#pragma unroll
        for (int mi = 0; mi < 2; ++mi)
          st[mi][nf] = MFMA(kf[nf][kk], qf[mi][kk], st[mi][nf]);
    __builtin_amdgcn_s_setprio(0);

    // prefetch K for tile t+1 into kf (WAR on issued MFMAs; hides under
    // softmax + PV)
    if (t + 1 < nt) {
      const int kvn = kv0 + 64;
#pragma unroll
      for (int nf = 0; nf < 4; ++nf)
#pragma unroll
        for (int kk = 0; kk < 2; ++kk)
          kf[nf][kk] = *(const bf8v*)(Kh + (size_t)(kvn + nf * 16 + col) * D_ + kk * 32 + grp * 8);
    }

    if (t == nt - 1) {  // causal mask: only the diagonal tile straddles
#pragma unroll
      for (int mi = 0; mi < 2; ++mi) {
        const int q = qmin + mi * 16 + col;
#pragma unroll
        for (int nf = 0; nf < 4; ++nf)
#pragma unroll
          for (int reg = 0; reg < 4; ++reg) {
            int kv = kv0 + nf * 16 + grp * 4 + reg;
            if (kv > q) st[mi][nf][reg] = -INFINITY;
          }
      }
    }

    // online softmax: lane owns q=col+16mi; 16 in-lane values + 2 shfl
#pragma unroll
    for (int mi = 0; mi < 2; ++mi) {
      float tm = st[mi][0][0];
#pragma unroll
      for (int nf = 0; nf < 4; ++nf) {
        tm = fmaxf(tm, fmaxf(fmaxf(st[mi][nf][0], st[mi][nf][1]),
                             fmaxf(st[mi][nf][2], st[mi][nf][3])));
      }
      tm = fmaxf(tm, __shfl_xor(tm, 16));
      tm = fmaxf(tm, __shfl_xor(tm, 32));
      float mnew = fmaxf(mrow[mi], tm);
      float corr = __expf(mrow[mi] - mnew);
      float ps = 0.f;
#pragma unroll
      for (int nf = 0; nf < 4; ++nf)
#pragma unroll
        for (int reg = 0; reg < 4; ++reg) {
          float p = __expf(st[mi][nf][reg] - mnew);
          st[mi][nf][reg] = p;
          ps += p;
        }
      ps += __shfl_xor(ps, 16);
      ps += __shfl_xor(ps, 32);
      lrow[mi] = lrow[mi] * corr + ps;
      mrow[mi] = mnew;
#pragma unroll
      for (int nf = 0; nf < 4; ++nf) o[mi][nf] *= corr;

      // P write: lane holds P[q][kv=nf*16+grp*4+reg] -> 4 consecutive kv
      const int q32 = mi * 16 + col;
#pragma unroll
      for (int nf = 0; nf < 4; ++nf) {
        ushort4 pv;
        pv.x = f2bf(st[mi][nf][0]);
        pv.y = f2bf(st[mi][nf][1]);
        pv.z = f2bf(st[mi][nf][2]);
        pv.w = f2bf(st[mi][nf][3]);
        const int slot = (nf * 2 + (grp >> 1)) ^ (q32 & 7);
        *(ushort4*)(pw + q32 * 64 + slot * 8 + (grp & 1) * 4) = pv;
      }
    }

    // P read (B-operand): lane needs P[q=col+16mi][kv=kk*32+grp*8..] (b128)
    bf8v pf[2][2];
#pragma unroll
    for (int mi = 0; mi < 2; ++mi) {
      const int q32 = mi * 16 + col;
#pragma unroll
      for (int kk = 0; kk < 2; ++kk) {
        const int slot = (kk * 4 + grp) ^ (q32 & 7);
        pf[mi][kk] = *(const bf8v*)(pw + q32 * 64 + slot * 8);
      }
    }

    __builtin_amdgcn_s_setprio(1);
#pragma unroll
    for (int kk = 0; kk < 2; ++kk)
#pragma unroll
      for (int nf = 0; nf < 4; ++nf)
#pragma unroll
        for (int mi = 0; mi < 2; ++mi)
          o[mi][nf] = MFMA(vf[nf][kk], pf[mi][kk], o[mi][nf]);
    __builtin_amdgcn_s_setprio(0);
  }

  // epilogue: O^T layout col q = col+16mi, row d = nf*16+grp*4+reg
#pragma unroll
  for (int mi = 0; mi < 2; ++mi) {
    const float inv = 1.f / lrow[mi];
    const int q = qmin + mi * 16 + col;
#pragma unroll
    for (int nf = 0; nf < 4; ++nf) {
      ushort4 ov;
      ov.x = f2bf(o[mi][nf][0] * inv);
      ov.y = f2bf(o[mi][nf][1] * inv);
      ov.z = f2bf(o[mi][nf][2] * inv);
      ov.w = f2bf(o[mi][nf][3] * inv);
      *(ushort4*)&ctxh[(size_t)q * DM + nf * 16 + grp * 4] = ov;
    }
  }
}

__global__ __launch_bounds__(256, 2) void k_attn(
    const u16* __restrict__ Q, const u16* __restrict__ K, const u16* __restrict__ VT,
    u16* __restrict__ ctx) {
  __shared__ u16 sP[4][32 * 64];  // per-wave P buffer, XOR-swizzled 16B slots
  const int g = blockIdx.x;                  // 512 blocks
  const int xcd = g & 7, idx = g >> 3;       // idx 0..63
  const int bh = xcd * 8 + (idx >> 3);       // 8 consecutive bh per XCD
  const int tid = threadIdx.x, lane = tid & 63, w = tid >> 6;
  const int p = (idx & 7) * 4 + w;           // pair index 0..31
  const int col = lane & 15, grp = lane >> 4;

  const u16* Qh = Q + (size_t)bh * S_ * D_;
  const u16* Kh = K + (size_t)bh * S_ * D_;
  const u16* Vh = VT + (size_t)bh * D_ * S_;
  u16* ctxh = ctx + ((size_t)(bh >> 4) * S_) * DM + (bh & 15) * 64;
  u16* pw = sP[w];

  // balanced pair: cost (p/2+1) + ((63-p)/2+1) = 33 tiles for every wave
  attn_job(Qh, Kh, Vh, ctxh, 32 * p, pw, col, grp);
  attn_job(Qh, Kh, Vh, ctxh, 32 * (63 - p), pw, col, grp);
}

// ---------------- output projection (fp32 out) ----------------
__global__ __launch_bounds__(256, 2) void k_oproj(
    const u16* __restrict__ ctx, const u16* __restrict__ woT,
    const float* __restrict__ bo, float* __restrict__ out) {
  __shared__ u16 sA[128 * 64], sB[128 * 64];
  const int mbase = blockIdx.y * 128, nbase = blockIdx.x * 128;
  f32x4 acc[4][4];
#pragma unroll
  for (int i = 0; i < 4; ++i)
#pragma unroll
    for (int j = 0; j < 4; ++j) acc[i][j] = (f32x4){0.f, 0.f, 0.f, 0.f};

  gemm_main(ctx, woT, mbase, nbase, sA, sB, acc);

  const int lane = threadIdx.x & 63, w = threadIdx.x >> 6;
  const int wm = w >> 1, wn = w & 1;
  const int ksl = lane >> 4, rA = lane & 15;
#pragma unroll
  for (int nf = 0; nf < 4; ++nf) {
    const int n = nbase + wn * 64 + nf * 16 + rA;
    const float bb = bo[n];
#pragma unroll
    for (int mi = 0; mi < 4; ++mi) {
      const int m0 = mbase + wm * 64 + mi * 16 + ksl * 4;
#pragma unroll
      for (int reg = 0; reg < 4; ++reg)
        out[(size_t)(m0 + reg) * DM + n] = acc[mi][nf][reg] + bb;
    }
  }
}

extern "C" void kernel_launch(void* const* d_in, const int* in_sizes, int n_in,
                              void* d_out, int out_size, void* d_ws, size_t ws_size,
                              hipStream_t stream) {
  const float* x  = (const float*)d_in[0];
  const float* Wq = (const float*)d_in[1];
  const float* bq = (const float*)d_in[2];
  const float* Wk = (const float*)d_in[3];
  const float* bk = (const float*)d_in[4];
  const float* Wv = (const float*)d_in[5];
  const float* bv = (const float*)d_in[6];
  const float* Wo = (const float*)d_in[7];
  const float* bo = (const float*)d_in[8];
  float* out = (float*)d_out;

  char* ws = (char*)d_ws;
  u16* xb  = (u16*)(ws);
  u16* wqT = (u16*)(ws + (size_t)(16u << 20));
  u16* wkT = (u16*)(ws + (size_t)(18u << 20));
  u16* wvT = (u16*)(ws + (size_t)(20u << 20));
  u16* woT = (u16*)(ws + (size_t)(22u << 20));
  u16* Qd  = (u16*)(ws + (size_t)(24u << 20));
  u16* Kd  = (u16*)(ws + (size_t)(40u << 20));
  u16* VTd = (u16*)(ws + (size_t)(56u << 20));
  u16* ctx = xb;  // xb dead after k_qkv; stream-ordered reuse

  k_cvt_x<<<2048, 256, 0, stream>>>(x, xb, (8192 * 1024) / 4);
  k_cvt_wT4<<<dim3(16, 16, 4), dim3(64, 4), 0, stream>>>(Wq, Wk, Wv, Wo, wqT, wkT, wvT, woT);
  k_qkv<<<dim3(8, 64, 3), 256, 0, stream>>>(xb, wqT, wkT, wvT, bq, bk, bv, Qd, Kd, VTd);
  k_attn<<<512, 256, 0, stream>>>(Qd, Kd, VTd, ctx);
  k_oproj<<<dim3(8, 64), 256, 0, stream>>>(ctx, woT, bo, out);
}